// Round 8
// baseline (401.472 us; speedup 1.0000x reference)
//
#include <hip/hip_runtime.h>
#include <limits.h>

#define HH 128
#define WW_ 128
#define HW 16384
#define NB 16
#define CF 192
#define H2 64
#define W2 64
#define SH 16          // strip height
#define NS 8           // strips per image
#define SRUN 1024      // run-id space per strip (16 rows * 64 runs)
#define GSPACE 8192    // merged id space per image (8 strips * 1024)

typedef float vf4 __attribute__((ext_vector_type(4)));
typedef unsigned long long ull;

// ---------------------------------------------------------------------------
// Union-find on an LDS parent array. Links always go high->low id -> chains
// strictly decrease -> concurrent path halving is safe and terminating.
// ---------------------------------------------------------------------------

__device__ inline int uf_find(int* par, int x) {
    volatile int* vp = (volatile int*)par;
    int p = vp[x];
    while (p != x) {
        int g = vp[p];
        vp[x] = g;
        x = g;
        p = vp[x];
    }
    return x;
}

__device__ inline void uf_union(int* par, int a, int b) {
    int ra = uf_find(par, a);
    int rb = uf_find(par, b);
    while (ra != rb) {
        if (ra < rb) { int t = ra; ra = rb; rb = t; }
        int old = atomicCAS(&par[ra], ra, rb);
        if (old == ra) return;
        ra = uf_find(par, old);
        rb = uf_find(par, rb);
    }
}

// walk to terminal: claimed marker (>= thr) or unclaimed root id
__device__ inline int walk_term(int* par, int x, int thr) {
    volatile int* vp = (volatile int*)par;
    int p = vp[x];
    while (p < thr && p != x) { x = p; p = vp[x]; }
    return (p >= thr) ? p : x;
}

// ---------------------------------------------------------------------------
// 128-bit row mask helpers (lo = cols 0..63, hi = cols 64..127)
// ---------------------------------------------------------------------------

__device__ inline int getbit2(ull lo, ull hi, int c) {
    return (int)(((c < 64) ? (lo >> c) : (hi >> (c - 64))) & 1ULL);
}

__device__ inline int leading_ones(ull v) {
    ull nv = ~v;
    return (nv == 0ULL) ? 64 : __clzll(nv);
}

__device__ inline int trailing_ones(ull v) {
    ull nv = ~v;
    return (nv == 0ULL) ? 64 : (__ffsll(nv) - 1);
}

__device__ inline int run_start_col(ull lo, ull hi, int c) {
    if (c < 64) {
        int ones = leading_ones(lo << (63 - c));
        return c - ones + 1;
    }
    int ones = leading_ones(hi << (127 - c));
    int rs = c - ones + 1;
    if (rs == 64) rs -= leading_ones(lo);
    return rs;
}

__device__ inline int run_end_col(ull lo, ull hi, int c) {
    if (c >= 64) {
        return c + trailing_ones(hi >> (c - 64)) - 1;
    }
    int e = c + trailing_ones(lo >> c) - 1;
    if (e == 63) e += trailing_ones(hi);
    return e;
}

__device__ inline int run_index(ull rs_lo, ull rs_hi, int cs) {
    if (cs < 64)  return __popcll(rs_lo & ((1ULL << cs) - 1ULL));
    if (cs == 64) return __popcll(rs_lo);
    return __popcll(rs_lo) + __popcll(rs_hi & ((1ULL << (cs - 64)) - 1ULL));
}

// 128-bit mask of bits [a, b] inclusive, 0 <= a <= b <= 127
__device__ inline void span_mask(int a, int b, ull& mlo, ull& mhi) {
    ull one = ~0ULL;
    int bl = (b < 63) ? b : 63;
    mlo = (a <= 63) ? (((bl == 63) ? one : ((1ULL << (bl + 1)) - 1)) & ~((1ULL << a) - 1)) : 0ULL;
    if (b >= 64) {
        int a2 = (a >= 64) ? a - 64 : 0;
        int b2 = b - 64;
        mhi = ((b2 == 63) ? one : ((1ULL << (b2 + 1)) - 1)) & ~((1ULL << a2) - 1);
    } else mhi = 0ULL;
}

__device__ inline void top3_ins(float s, int id, int x,
    float& s0, float& s1, float& s2,
    int& i0, int& i1, int& i2,
    int& x0, int& x1, int& x2)
{
    if (x < 0) return;
    if (s > s0 || (s == s0 && id < i0)) {
        s2 = s1; i2 = i1; x2 = x1;
        s1 = s0; i1 = i0; x1 = x0;
        s0 = s;  i0 = id; x0 = x;
    } else if (s > s1 || (s == s1 && id < i1)) {
        s2 = s1; i2 = i1; x2 = x1;
        s1 = s;  i1 = id; x1 = x;
    } else if (s > s2 || (s == s2 && id < i2)) {
        s2 = s;  i2 = id; x2 = x;
    }
}

// ---------------------------------------------------------------------------
// Kernel A: 128 blocks (16 images x 8 strips of 16 rows). Independent
// in-LDS run-UF CCL per strip + per-local-component stats; emits compact
// records + boundary-row run->component maps + boundary masks.
// ---------------------------------------------------------------------------

__global__ __launch_bounds__(256) void strip_kernel(
    const float* __restrict__ prob,
    int* __restrict__ ncomp,
    int* __restrict__ rec_cnt, float* __restrict__ rec_conf,
    int* __restrict__ rec_minr, int* __restrict__ rec_maxr,
    int* __restrict__ rec_minc, int* __restrict__ rec_maxc,
    int* __restrict__ rec_maxid,
    int* __restrict__ topmap, int* __restrict__ botmap,
    ull* __restrict__ bmasks)
{
    __shared__ ull rowmask[SH][2], rsmask[SH][2];
    __shared__ int nrunrow[SH];
    __shared__ int parent[SRUN];
    __shared__ int   lcnt[SRUN];
    __shared__ float lconf[SRUN];
    __shared__ int lminr[SRUN], lmaxr[SRUN], lminc[SRUN], lmaxc[SRUN], lmaxid[SRUN];
    __shared__ int sn;

    const int sg = blockIdx.x;           // strip global id 0..127
    const int b = sg >> 3, s = sg & 7;
    const int row0 = s * SH;
    const int tid = threadIdx.x, lane = tid & 63, wv = tid >> 6;
    const float* p = prob + (size_t)b * HW + (size_t)row0 * WW_;

    if (tid == 0) sn = 0;

    // P0: masks (wave wv covers rows wv*4..wv*4+3) + parent init
    #pragma unroll
    for (int k = 0; k < 4; ++k) {
        int row = wv * 4 + k;
        ull m0 = __ballot(p[(row << 7) + lane] > 0.5f);
        ull m1 = __ballot(p[(row << 7) + 64 + lane] > 0.5f);
        if (lane == 0) {
            rowmask[row][0] = m0; rowmask[row][1] = m1;
            ull rs_lo = m0 & ~(m0 << 1);
            ull rs_hi = m1 & ~((m1 << 1) | (m0 >> 63));
            rsmask[row][0] = rs_lo; rsmask[row][1] = rs_hi;
            nrunrow[row] = __popcll(rs_lo) + __popcll(rs_hi);
        }
    }
    #pragma unroll
    for (int k = 0; k < SRUN / 256; ++k)
        parent[k * 256 + tid] = k * 256 + tid;
    __syncthreads();

    // P2: intra-strip unions (rows 1..15), run-centric span intersection
    if (tid < 128) {
        int row = tid >> 3, w0 = (tid & 7) * 16;
        if (row > 0) {
            ull lo = rowmask[row][0], hi = rowmask[row][1];
            ull rs_lo = rsmask[row][0], rs_hi = rsmask[row][1];
            ull seg = ((w0 < 64) ? (rs_lo >> w0) : (rs_hi >> (w0 - 64))) & 0xFFFFULL;
            if (seg) {
                ull ulo = rowmask[row - 1][0], uhi = rowmask[row - 1][1];
                ull urs_lo = rsmask[row - 1][0], urs_hi = rsmask[row - 1][1];
                int ub = (row - 1) << 6;
                while (seg) {
                    int c = w0 + (__ffsll(seg) - 1);
                    seg &= seg - 1;
                    int e = run_end_col(lo, hi, c);
                    int rid = (row << 6) + run_index(rs_lo, rs_hi, c);
                    int a0 = (c > 0) ? c - 1 : 0;
                    int a1 = (e < 127) ? e + 1 : 127;
                    if (getbit2(ulo, uhi, a0))
                        uf_union(parent, rid,
                                 ub + run_index(urs_lo, urs_hi, run_start_col(ulo, uhi, a0)));
                    if (a1 > a0) {
                        ull mlo, mhi;
                        span_mask(a0 + 1, a1, mlo, mhi);
                        ull h_lo = urs_lo & mlo, h_hi = urs_hi & mhi;
                        while (h_lo) {
                            int cs = __ffsll(h_lo) - 1; h_lo &= h_lo - 1;
                            uf_union(parent, rid, ub + run_index(urs_lo, urs_hi, cs));
                        }
                        while (h_hi) {
                            int cs = 64 + __ffsll(h_hi) - 1; h_hi &= h_hi - 1;
                            uf_union(parent, rid, ub + run_index(urs_lo, urs_hi, cs));
                        }
                    }
                }
            }
        }
    }
    __syncthreads();

    // P3: merged flatten + dense-index claim (marker >= SRUN)
    for (int rid = tid; rid < SRUN; rid += 256) {
        bool valid = (rid & 63) < nrunrow[rid >> 6];
        bool isroot = valid && parent[rid] == rid;
        ull m = __ballot(isroot);
        if (m) {
            int baseIdx = 0;
            if (lane == 0) baseIdx = atomicAdd(&sn, __popcll(m));
            baseIdx = __shfl(baseIdx, 0);
            if (isroot)
                parent[rid] = SRUN + baseIdx + __popcll(m & ((1ULL << lane) - 1ULL));
        }
        if (valid && !isroot)
            parent[rid] = walk_term(parent, rid, SRUN);
    }
    __syncthreads();

    const int n = sn;
    for (int j = tid; j < n; j += 256) {
        lcnt[j] = 0; lconf[j] = 0.f;
        lminr[j] = INT_MAX; lmaxr[j] = -1;
        lminc[j] = INT_MAX; lmaxc[j] = -1;
        lmaxid[j] = 0;
    }
    __syncthreads();

    // P4: per-run stats (global row coordinates; maxid stored as idx+1)
    if (tid < 128) {
        int row = tid >> 3, w0 = (tid & 7) * 16;
        int gr = row0 + row;
        ull lo = rowmask[row][0], hi = rowmask[row][1];
        ull rs_lo = rsmask[row][0], rs_hi = rsmask[row][1];
        ull seg = ((w0 < 64) ? (rs_lo >> w0) : (rs_hi >> (w0 - 64))) & 0xFFFFULL;
        while (seg) {
            int c = w0 + (__ffsll(seg) - 1);
            seg &= seg - 1;
            int e = run_end_col(lo, hi, c);
            int rid = (row << 6) + run_index(rs_lo, rs_hi, c);
            int v = parent[rid];
            int idx = (v >= SRUN) ? (v - SRUN) : (parent[v] - SRUN);
            float sum = 0.f;
            for (int j = c; j <= e; ++j) sum += p[(row << 7) + j];
            atomicAdd(&lcnt[idx], e - c + 1);
            atomicAdd(&lconf[idx], sum);
            atomicMin(&lminr[idx], gr);
            atomicMax(&lmaxr[idx], gr);
            atomicMin(&lminc[idx], c);
            atomicMax(&lmaxc[idx], e);
            atomicMax(&lmaxid[idx], (gr << 7) + e + 1);
        }
    }
    __syncthreads();

    // P5: emit records, boundary maps, boundary masks
    const size_t rb = (size_t)sg * SRUN;
    for (int d = tid; d < n; d += 256) {
        rec_cnt[rb + d]   = lcnt[d];
        rec_conf[rb + d]  = lconf[d];
        rec_minr[rb + d]  = lminr[d];
        rec_maxr[rb + d]  = lmaxr[d];
        rec_minc[rb + d]  = lminc[d];
        rec_maxc[rb + d]  = lmaxc[d];
        rec_maxid[rb + d] = lmaxid[d];
    }
    if (tid == 0) ncomp[sg] = n;
    if (tid < 64) {
        if (tid < nrunrow[0]) {
            int v = parent[tid];
            topmap[sg * 64 + tid] = (v >= SRUN) ? (v - SRUN) : (parent[v] - SRUN);
        }
        if (tid < nrunrow[SH - 1]) {
            int rid = ((SH - 1) << 6) + tid;
            int v = parent[rid];
            botmap[sg * 64 + tid] = (v >= SRUN) ? (v - SRUN) : (parent[v] - SRUN);
        }
    }
    if (tid >= 64 && tid < 72) {
        int k = tid - 64;
        ull v = 0;
        switch (k) {
            case 0: v = rowmask[0][0]; break;
            case 1: v = rowmask[0][1]; break;
            case 2: v = rsmask[0][0];  break;
            case 3: v = rsmask[0][1];  break;
            case 4: v = rowmask[SH-1][0]; break;
            case 5: v = rowmask[SH-1][1]; break;
            case 6: v = rsmask[SH-1][0];  break;
            case 7: v = rsmask[SH-1][1];  break;
        }
        bmasks[sg * 8 + k] = v;
    }
}

// ---------------------------------------------------------------------------
// Kernel B: 16 blocks (one per image). Merge the 7 strip boundaries in an
// 8192-slot LDS UF, aggregate cnt/conf/maxid into roots, top-3 + K rules,
// rebuild winner bboxes from strip records, write 3 bboxes.
// ---------------------------------------------------------------------------

__global__ __launch_bounds__(1024) void merge_kernel(
    const int* __restrict__ ncomp,
    const int* __restrict__ rec_cnt, const float* __restrict__ rec_conf,
    const int* __restrict__ rec_minr, const int* __restrict__ rec_maxr,
    const int* __restrict__ rec_minc, const int* __restrict__ rec_maxc,
    const int* __restrict__ rec_maxid,
    const int* __restrict__ topmap, const int* __restrict__ botmap,
    const ull* __restrict__ bmasks,
    int* __restrict__ bbox)
{
    __shared__ int parent[GSPACE];        // 32 KB
    __shared__ int   lcnt[GSPACE];        // 32 KB
    __shared__ float lconf[GSPACE];       // 32 KB
    __shared__ int lmaxid[GSPACE];        // 32 KB
    __shared__ int nc[NS];
    __shared__ float wss[48];
    __shared__ int wid_[48], wrx[48];
    __shared__ int winner[3], w_minr[3], w_maxr[3], w_minc[3], w_maxc[3];
    __shared__ int sK;

    const int b = blockIdx.x;
    const int tid = threadIdx.x, lane = tid & 63;

    if (tid == 0) sK = 0;
    if (tid < NS) nc[tid] = ncomp[b * 8 + tid];
    __syncthreads();

    // init parent + stats from records
    for (int g = tid; g < GSPACE; g += 1024) {
        parent[g] = g;
        int s = g >> 10, d = g & 1023;
        if (d < nc[s]) {
            size_t rb = (size_t)(b * 8 + s) * SRUN + d;
            lcnt[g] = rec_cnt[rb];
            lconf[g] = rec_conf[rb];
            lmaxid[g] = rec_maxid[rb];
        }
    }
    __syncthreads();

    // boundary unions: 7 boundaries x 8 windows = 56 work items
    if (tid < 56) {
        int i = tid >> 3, w0 = (tid & 7) * 16;
        int sgb = b * 8 + i;          // strip providing bottom row
        int sgt = b * 8 + i + 1;      // strip providing top row
        ull tm_lo = bmasks[sgt*8+0], tm_hi = bmasks[sgt*8+1];
        ull trs_lo = bmasks[sgt*8+2], trs_hi = bmasks[sgt*8+3];
        ull bm_lo = bmasks[sgb*8+4], bm_hi = bmasks[sgb*8+5];
        ull brs_lo = bmasks[sgb*8+6], brs_hi = bmasks[sgb*8+7];
        ull seg = ((w0 < 64) ? (trs_lo >> w0) : (trs_hi >> (w0 - 64))) & 0xFFFFULL;
        while (seg) {
            int c = w0 + (__ffsll(seg) - 1);
            seg &= seg - 1;
            int e = run_end_col(tm_lo, tm_hi, c);
            int g_top = ((i + 1) << 10) + topmap[sgt * 64 + run_index(trs_lo, trs_hi, c)];
            int a0 = (c > 0) ? c - 1 : 0;
            int a1 = (e < 127) ? e + 1 : 127;
            if (getbit2(bm_lo, bm_hi, a0)) {
                int g_bot = (i << 10) +
                    botmap[sgb * 64 + run_index(brs_lo, brs_hi, run_start_col(bm_lo, bm_hi, a0))];
                uf_union(parent, g_top, g_bot);
            }
            if (a1 > a0) {
                ull mlo, mhi;
                span_mask(a0 + 1, a1, mlo, mhi);
                ull h_lo = brs_lo & mlo, h_hi = brs_hi & mhi;
                while (h_lo) {
                    int cs = __ffsll(h_lo) - 1; h_lo &= h_lo - 1;
                    uf_union(parent, g_top, (i << 10) + botmap[sgb * 64 + run_index(brs_lo, brs_hi, cs)]);
                }
                while (h_hi) {
                    int cs = 64 + __ffsll(h_hi) - 1; h_hi &= h_hi - 1;
                    uf_union(parent, g_top, (i << 10) + botmap[sgb * 64 + run_index(brs_lo, brs_hi, cs)]);
                }
            }
        }
    }
    __syncthreads();

    // flatten
    for (int g = tid; g < GSPACE; g += 1024) {
        int s = g >> 10, d = g & 1023;
        if (d < nc[s]) parent[g] = uf_find(parent, g);
    }
    __syncthreads();

    // merge stats into roots (non-root entries are only read by their owner)
    for (int g = tid; g < GSPACE; g += 1024) {
        int s = g >> 10, d = g & 1023;
        if (d < nc[s]) {
            int rg = parent[g];
            if (rg != g) {
                atomicAdd(&lcnt[rg], lcnt[g]);
                atomicAdd(&lconf[rg], lconf[g]);
                atomicMax(&lmaxid[rg], lmaxid[g]);
            }
        }
    }
    __syncthreads();

    // top-3 over final roots + K count
    {
        float s0 = -INFINITY, s1 = -INFINITY, s2 = -INFINITY;
        int i0 = INT_MAX, i1 = INT_MAX, i2 = INT_MAX;
        int x0 = -1, x1 = -1, x2 = -1;
        int myK = 0;
        for (int g = tid; g < GSPACE; g += 1024) {
            int s = g >> 10, d = g & 1023;
            if (d < nc[s] && parent[g] == g) {
                myK++;
                float sc = lconf[g] / (float)lcnt[g];
                top3_ins(sc, lmaxid[g], g, s0, s1, s2, i0, i1, i2, x0, x1, x2);
            }
        }
        for (int off = 32; off; off >>= 1) {
            float bs0 = __shfl_xor(s0, off), bs1 = __shfl_xor(s1, off), bs2 = __shfl_xor(s2, off);
            int bi0 = __shfl_xor(i0, off), bi1 = __shfl_xor(i1, off), bi2 = __shfl_xor(i2, off);
            int bx0 = __shfl_xor(x0, off), bx1 = __shfl_xor(x1, off), bx2 = __shfl_xor(x2, off);
            myK += __shfl_xor(myK, off);
            top3_ins(bs0, bi0, bx0, s0, s1, s2, i0, i1, i2, x0, x1, x2);
            top3_ins(bs1, bi1, bx1, s0, s1, s2, i0, i1, i2, x0, x1, x2);
            top3_ins(bs2, bi2, bx2, s0, s1, s2, i0, i1, i2, x0, x1, x2);
        }
        if (lane == 0) {
            int w = tid >> 6;
            wss[w * 3 + 0] = s0; wid_[w * 3 + 0] = i0; wrx[w * 3 + 0] = x0;
            wss[w * 3 + 1] = s1; wid_[w * 3 + 1] = i1; wrx[w * 3 + 1] = x1;
            wss[w * 3 + 2] = s2; wid_[w * 3 + 2] = i2; wrx[w * 3 + 2] = x2;
            atomicAdd(&sK, myK);
        }
    }
    __syncthreads();

    if (tid == 0) {
        float t0 = -INFINITY, t1 = -INFINITY, t2 = -INFINITY;
        int ti0 = INT_MAX, ti1 = INT_MAX, ti2 = INT_MAX;
        int tx0 = -1, tx1 = -1, tx2 = -1;
        for (int t = 0; t < 48; ++t)
            top3_ins(wss[t], wid_[t], wrx[t], t0, t1, t2, ti0, ti1, ti2, tx0, tx1, tx2);
        int K = sK;
        if (K >= 3)      { winner[0] = tx0; winner[1] = tx1; winner[2] = tx2; }
        else if (K == 2) { winner[0] = tx0; winner[1] = tx0; winner[2] = tx1; }
        else if (K == 1) { winner[0] = tx0; winner[1] = tx0; winner[2] = tx0; }
        else             { winner[0] = -1;  winner[1] = -1;  winner[2] = -1;  }
    }
    if (tid >= 64 && tid < 67) {
        int s = tid - 64;
        w_minr[s] = INT_MAX; w_maxr[s] = -1;
        w_minc[s] = INT_MAX; w_maxc[s] = -1;
    }
    __syncthreads();

    // winner bbox rebuild from strip records
    {
        int wn0 = winner[0], wn1 = winner[1], wn2 = winner[2];
        for (int g = tid; g < GSPACE; g += 1024) {
            int s = g >> 10, d = g & 1023;
            if (d >= nc[s]) continue;
            int rg = parent[g];
            if (rg != wn0 && rg != wn1 && rg != wn2) continue;
            size_t rb = (size_t)(b * 8 + s) * SRUN + d;
            int mnr = rec_minr[rb], mxr = rec_maxr[rb];
            int mnc = rec_minc[rb], mxc = rec_maxc[rb];
            #pragma unroll
            for (int sl = 0; sl < 3; ++sl) {
                int wn = (sl == 0) ? wn0 : (sl == 1) ? wn1 : wn2;
                if (rg == wn) {
                    atomicMin(&w_minr[sl], mnr);
                    atomicMax(&w_maxr[sl], mxr);
                    atomicMin(&w_minc[sl], mnc);
                    atomicMax(&w_maxc[sl], mxc);
                }
            }
        }
    }
    __syncthreads();

    if (tid < 3) {
        int sl = tid;
        int mr, h, mc, w;
        if (winner[sl] < 0) { mr = 0; h = HH; mc = 0; w = WW_; }
        else {
            mr = w_minr[sl]; h = w_maxr[sl] + 1 - mr;
            mc = w_minc[sl]; w = w_maxc[sl] + 1 - mc;
        }
        int* o = bbox + (b * 3 + sl) * 4;
        o[0] = mr; o[1] = h; o[2] = mc; o[3] = w;
    }
}

// ---------------------------------------------------------------------------
// Kernel C: nearest-neighbor crop-resize gather. 2 x float4 per thread.
// out[b, slot*192+c, y, x] = feat[b, c, mr + (y*h)>>6, mc + (x*w)>>6]
// ---------------------------------------------------------------------------

__global__ __launch_bounds__(256) void crop_kernel(
    const float* __restrict__ feat, const int* __restrict__ bbox,
    float* __restrict__ out)
{
    const int gid = blockIdx.x * 256 + threadIdx.x;
    const int o4 = gid * 2;
    const int x4 = o4 & 15;
    const int y  = (o4 >> 4) & 63;
    const int t  = o4 >> 10;
    const int c  = t % CF;
    const int bs = t / CF;
    const int* bb = bbox + bs * 4;
    const int mr = bb[0], h = bb[1], mc = bb[2], w = bb[3];
    const int r = mr + ((y * h) >> 6);
    const int bimg = bs / 3;
    const float* row = feat + (((size_t)bimg * CF + c) * HH + r) * WW_;
    const int x = x4 * 4;
    vf4 v0, v1;
    v0.x = row[mc + (((x + 0) * w) >> 6)];
    v0.y = row[mc + (((x + 1) * w) >> 6)];
    v0.z = row[mc + (((x + 2) * w) >> 6)];
    v0.w = row[mc + (((x + 3) * w) >> 6)];
    v1.x = row[mc + (((x + 4) * w) >> 6)];
    v1.y = row[mc + (((x + 5) * w) >> 6)];
    v1.z = row[mc + (((x + 6) * w) >> 6)];
    v1.w = row[mc + (((x + 7) * w) >> 6)];
    __builtin_nontemporal_store(v0, (vf4*)out + o4);
    __builtin_nontemporal_store(v1, (vf4*)out + o4 + 1);
}

// ---------------------------------------------------------------------------

extern "C" void kernel_launch(void* const* d_in, const int* in_sizes, int n_in,
                              void* d_out, int out_size, void* d_ws, size_t ws_size,
                              hipStream_t stream) {
    const float* prob = (const float*)d_in[0];   // [16,1,128,128]
    const float* feat = (const float*)d_in[1];   // [16,192,128,128]
    float* out = (float*)d_out;                  // [16,576,64,64]

    char* ws = (char*)d_ws;
    const size_t NREC = 128 * (size_t)SRUN;      // 131072 entries
    int*   bbox      = (int*)(ws);                           // 768 B
    ull*   bmasks    = (ull*)(ws + 1024);                    // 8 KB
    int*   ncomp     = (int*)(ws + 1024 + 8192);             // 512 B
    int*   topmap    = (int*)(ws + 16384);                   // 32 KB
    int*   botmap    = (int*)(ws + 16384 + 32768);           // 32 KB
    char*  recbase   = ws + 16384 + 65536;
    int*   rec_cnt   = (int*)(recbase + 0 * NREC * 4);
    float* rec_conf  = (float*)(recbase + 1 * NREC * 4);
    int*   rec_minr  = (int*)(recbase + 2 * NREC * 4);
    int*   rec_maxr  = (int*)(recbase + 3 * NREC * 4);
    int*   rec_minc  = (int*)(recbase + 4 * NREC * 4);
    int*   rec_maxc  = (int*)(recbase + 5 * NREC * 4);
    int*   rec_maxid = (int*)(recbase + 6 * NREC * 4);

    hipLaunchKernelGGL(strip_kernel, dim3(NB * NS), dim3(256), 0, stream,
                       prob, ncomp, rec_cnt, rec_conf, rec_minr, rec_maxr,
                       rec_minc, rec_maxc, rec_maxid, topmap, botmap, bmasks);
    hipLaunchKernelGGL(merge_kernel, dim3(NB), dim3(1024), 0, stream,
                       ncomp, rec_cnt, rec_conf, rec_minr, rec_maxr,
                       rec_minc, rec_maxc, rec_maxid, topmap, botmap, bmasks,
                       bbox);
    const int total4 = NB * 3 * CF * H2 * (W2 / 4);   // 9,437,184 float4s
    hipLaunchKernelGGL(crop_kernel, dim3(total4 / 512), dim3(256), 0, stream,
                       feat, bbox, out);
}

// Round 9
// 386.987 us; speedup vs baseline: 1.0374x; 1.0374x over previous
//
#include <hip/hip_runtime.h>
#include <limits.h>

#define HH 128
#define WW_ 128
#define HW 16384
#define NB 16
#define CF 192
#define H2 64
#define W2 64
#define NRUN 8192     // max runs: 128 rows * 64 runs/row
#define NCOMP 4096    // max 8-connected components in 128x128

typedef float vf4 __attribute__((ext_vector_type(4)));
typedef unsigned long long ull;

// ---------------------------------------------------------------------------
// Union-find on LDS parent array indexed by run id = (row<<6) | runIdxInRow.
// Links always go high->low id -> chains strictly decrease -> concurrent
// path halving is safe and terminating.
// ---------------------------------------------------------------------------

__device__ inline int uf_find(int* par, int x) {
    volatile int* vp = (volatile int*)par;
    int p = vp[x];
    while (p != x) {
        int g = vp[p];
        vp[x] = g;      // path halving: writes an ancestor, safe under races
        x = g;
        p = vp[x];
    }
    return x;
}

__device__ inline void uf_union(int* par, int a, int b) {
    int ra = uf_find(par, a);
    int rb = uf_find(par, b);
    while (ra != rb) {
        if (ra < rb) { int t = ra; ra = rb; rb = t; }   // link larger -> smaller
        int old = atomicCAS(&par[ra], ra, rb);
        if (old == ra) return;
        ra = uf_find(par, old);
        rb = uf_find(par, rb);
    }
}

// ---------------------------------------------------------------------------
// 128-bit row mask helpers (lo = cols 0..63, hi = cols 64..127)
// ---------------------------------------------------------------------------

__device__ inline int getbit2(ull lo, ull hi, int c) {
    return (int)(((c < 64) ? (lo >> c) : (hi >> (c - 64))) & 1ULL);
}

__device__ inline int leading_ones(ull v) {
    ull nv = ~v;
    return (nv == 0ULL) ? 64 : __clzll(nv);
}

__device__ inline int trailing_ones(ull v) {
    ull nv = ~v;
    return (nv == 0ULL) ? 64 : (__ffsll(nv) - 1);
}

// column of the start of the fg run containing column c (bit c must be set)
__device__ inline int run_start_col(ull lo, ull hi, int c) {
    if (c < 64) {
        int ones = leading_ones(lo << (63 - c));
        return c - ones + 1;
    }
    int ones = leading_ones(hi << (127 - c));
    int rs = c - ones + 1;
    if (rs == 64) rs -= leading_ones(lo);
    return rs;
}

// column of the end of the fg run containing column c (bit c must be set)
__device__ inline int run_end_col(ull lo, ull hi, int c) {
    if (c >= 64) {
        return c + trailing_ones(hi >> (c - 64)) - 1;
    }
    int e = c + trailing_ones(lo >> c) - 1;
    if (e == 63) e += trailing_ones(hi);
    return e;
}

// 0-based index of the run starting at column cs (cs must be a run start)
__device__ inline int run_index(ull rs_lo, ull rs_hi, int cs) {
    if (cs < 64)  return __popcll(rs_lo & ((1ULL << cs) - 1ULL));
    if (cs == 64) return __popcll(rs_lo);
    return __popcll(rs_lo) + __popcll(rs_hi & ((1ULL << (cs - 64)) - 1ULL));
}

__device__ inline void top3_ins(float s, int id, int x,
    float& s0, float& s1, float& s2,
    int& i0, int& i1, int& i2,
    int& x0, int& x1, int& x2)
{
    if (x < 0) return;
    if (s > s0 || (s == s0 && id < i0)) {
        s2 = s1; i2 = i1; x2 = x1;
        s1 = s0; i1 = i0; x1 = x0;
        s0 = s;  i0 = id; x0 = x;
    } else if (s > s1 || (s == s1 && id < i1)) {
        s2 = s1; i2 = i1; x2 = x1;
        s1 = s;  i1 = id; x1 = x;
    } else if (s > s2 || (s == s2 && id < i2)) {
        s2 = s;  i2 = id; x2 = x;
    }
}

// ---------------------------------------------------------------------------
// Kernel 1 (R6 structure — best measured, 387 us total): one block per
// image. Run-based union-find CCL + stats + top-3 + bbox, all in LDS.
// Zero global atomics; only global output is 3 bboxes per image.
// ---------------------------------------------------------------------------

__global__ __launch_bounds__(1024) void ccl_kernel(
    const float* __restrict__ prob, int* __restrict__ bbox)
{
    __shared__ int parent[NRUN];          // 32 KB
    __shared__ float pbuf[HW];            // 64 KB
    __shared__ ull rowmask[HH][2];        // 2 KB
    __shared__ ull rsmask[HH][2];         // 2 KB
    __shared__ int nrunrow[HH];           // 0.5 KB
    __shared__ int   lcnt[NCOMP];         // 16 KB
    __shared__ float lconf[NCOMP];        // 16 KB
    __shared__ int lmaxid[NCOMP];         // 16 KB
    __shared__ int snroots;
    __shared__ float wss[48];
    __shared__ int wid_[48], wrx[48];
    __shared__ int winner[3];
    __shared__ int w_minr[3], w_maxr[3], w_minc[3], w_maxc[3];

    const int b = blockIdx.x;
    const int tid = threadIdx.x;
    const float* p = prob + (size_t)b * HW;

    if (tid == 0) snroots = 0;

    // P0: load prob -> LDS, fg bitmasks via ballot, parent self-init,
    // stats init. (each wave = half a row, coalesced)
    #pragma unroll
    for (int k = 0; k < HW / 1024; ++k) {
        int i = k * 1024 + tid;
        float v = p[i];
        pbuf[i] = v;
        ull m = __ballot(v > 0.5f);
        if ((tid & 63) == 0) rowmask[i >> 7][(i >> 6) & 1] = m;
    }
    #pragma unroll
    for (int k = 0; k < NRUN / 1024; ++k) parent[k * 1024 + tid] = k * 1024 + tid;
    for (int j = tid; j < NCOMP; j += 1024) {
        lcnt[j] = 0; lconf[j] = 0.f; lmaxid[j] = 0;
    }
    __syncthreads();

    // P0b: per-row run-start masks + run counts
    for (int r = tid; r < HH; r += 1024) {
        ull lo = rowmask[r][0], hi = rowmask[r][1];
        ull rs_lo = lo & ~(lo << 1);
        ull rs_hi = hi & ~((hi << 1) | (lo >> 63));
        rsmask[r][0] = rs_lo; rsmask[r][1] = rs_hi;
        nrunrow[r] = __popcll(rs_lo) + __popcll(rs_hi);
    }
    __syncthreads();

    // P2: vertical unions, fired once per (run, upper-run) contact pair
    for (int k = 0; k < HW / 1024; ++k) {
        int i = k * 1024 + tid;
        int r = i >> 7, c = i & 127;
        if (r == 0) continue;
        ull lo = rowmask[r][0], hi = rowmask[r][1];
        if (!getbit2(lo, hi, c)) continue;
        ull ulo = rowmask[r - 1][0], uhi = rowmask[r - 1][1];
        int l  = (c > 0)   ? getbit2(lo, hi, c - 1) : 0;
        int rt = (c < 127) ? getbit2(lo, hi, c + 1) : 0;
        int up = getbit2(ulo, uhi, c);
        int ul = (c > 0)   ? getbit2(ulo, uhi, c - 1) : 0;
        int ur = (c < 127) ? getbit2(ulo, uhi, c + 1) : 0;
        bool u1 = up && !(l && ul);          // leftmost-contact dedup
        bool u2 = !up && ul && !l;
        bool u3 = !up && ur && !rt;
        if (!(u1 | u2 | u3)) continue;
        ull rs_lo = rsmask[r][0], rs_hi = rsmask[r][1];
        ull urs_lo = rsmask[r - 1][0], urs_hi = rsmask[r - 1][1];
        int rid = (r << 6) + run_index(rs_lo, rs_hi, run_start_col(lo, hi, c));
        int ub = (r - 1) << 6;
        if (u1) uf_union(parent, rid, ub + run_index(urs_lo, urs_hi, run_start_col(ulo, uhi, c)));
        if (u2) uf_union(parent, rid, ub + run_index(urs_lo, urs_hi, run_start_col(ulo, uhi, c - 1)));
        if (u3) uf_union(parent, rid, ub + run_index(urs_lo, urs_hi, run_start_col(ulo, uhi, c + 1)));
    }
    __syncthreads();

    // P3a: flatten all runs to their root
    for (int rid = tid; rid < NRUN; rid += 1024)
        if ((rid & 63) < nrunrow[rid >> 6]) parent[rid] = uf_find(parent, rid);
    __syncthreads();

    // P3b: roots claim dense indices, wave-aggregated (1 atomicAdd/wave)
    for (int rid = tid; rid < NRUN; rid += 1024) {
        bool isroot = ((rid & 63) < nrunrow[rid >> 6]) && parent[rid] == rid;
        ull m = __ballot(isroot);
        int lane = tid & 63;
        int cntw = __popcll(m);
        int baseIdx = 0;
        if (lane == 0 && cntw) baseIdx = atomicAdd(&snroots, cntw);
        baseIdx = __shfl(baseIdx, 0);
        if (isroot)
            parent[rid] = NRUN + baseIdx + __popcll(m & ((1ULL << lane) - 1ULL));
    }
    __syncthreads();

    // P4: per-run cnt/conf/maxid into LDS dense arrays (thread = one 16-col
    // window of one row; full run [c,e] handled by the window owning its start)
    {
        int row = tid >> 3;
        int w0 = (tid & 7) * 16;
        ull lo = rowmask[row][0], hi = rowmask[row][1];
        ull rs_lo = rsmask[row][0], rs_hi = rsmask[row][1];
        ull seg = ((w0 < 64) ? (rs_lo >> w0) : (rs_hi >> (w0 - 64))) & 0xFFFFULL;
        while (seg) {
            int c = w0 + (__ffsll(seg) - 1);
            seg &= seg - 1;
            int e = run_end_col(lo, hi, c);
            int rid = (row << 6) + run_index(rs_lo, rs_hi, c);
            int v = parent[rid];
            int idx = (v >= NRUN) ? (v - NRUN) : (parent[v] - NRUN);
            float s = 0.f;
            for (int j = c; j <= e; ++j) s += pbuf[(row << 7) + j];
            atomicAdd(&lcnt[idx], e - c + 1);
            atomicAdd(&lconf[idx], s);
            atomicMax(&lmaxid[idx], (row << 7) + e + 1);   // maxid stored as idx+1
        }
    }
    __syncthreads();

    // P5: top-3 by (mean_conf desc, segment-id asc): thread scan -> wave
    // shfl_xor butterfly -> tid0 merge + K rules; winners -> LDS
    const int n = snroots;
    {
        float s0 = -INFINITY, s1 = -INFINITY, s2 = -INFINITY;
        int i0 = INT_MAX, i1 = INT_MAX, i2 = INT_MAX;
        int x0 = -1, x1 = -1, x2 = -1;
        for (int j = tid; j < n; j += 1024) {
            float s = lconf[j] / (float)lcnt[j];
            top3_ins(s, lmaxid[j], j, s0, s1, s2, i0, i1, i2, x0, x1, x2);
        }
        for (int off = 32; off; off >>= 1) {
            float bs0 = __shfl_xor(s0, off), bs1 = __shfl_xor(s1, off), bs2 = __shfl_xor(s2, off);
            int bi0 = __shfl_xor(i0, off), bi1 = __shfl_xor(i1, off), bi2 = __shfl_xor(i2, off);
            int bx0 = __shfl_xor(x0, off), bx1 = __shfl_xor(x1, off), bx2 = __shfl_xor(x2, off);
            top3_ins(bs0, bi0, bx0, s0, s1, s2, i0, i1, i2, x0, x1, x2);
            top3_ins(bs1, bi1, bx1, s0, s1, s2, i0, i1, i2, x0, x1, x2);
            top3_ins(bs2, bi2, bx2, s0, s1, s2, i0, i1, i2, x0, x1, x2);
        }
        if ((tid & 63) == 0) {
            int w = tid >> 6;
            wss[w * 3 + 0] = s0; wid_[w * 3 + 0] = i0; wrx[w * 3 + 0] = x0;
            wss[w * 3 + 1] = s1; wid_[w * 3 + 1] = i1; wrx[w * 3 + 1] = x1;
            wss[w * 3 + 2] = s2; wid_[w * 3 + 2] = i2; wrx[w * 3 + 2] = x2;
        }
        if (tid >= 64 && tid < 67) {    // init winner-bbox slots (diff wave)
            int s = tid - 64;
            w_minr[s] = INT_MAX; w_maxr[s] = -1;
            w_minc[s] = INT_MAX; w_maxc[s] = -1;
        }
    }
    __syncthreads();

    if (tid == 0) {
        float t0 = -INFINITY, t1 = -INFINITY, t2 = -INFINITY;
        int ti0 = INT_MAX, ti1 = INT_MAX, ti2 = INT_MAX;
        int tx0 = -1, tx1 = -1, tx2 = -1;
        for (int t = 0; t < 48; ++t)
            top3_ins(wss[t], wid_[t], wrx[t], t0, t1, t2, ti0, ti1, ti2, tx0, tx1, tx2);
        int K = n;
        if (K >= 3)      { winner[0] = tx0; winner[1] = tx1; winner[2] = tx2; }
        else if (K == 2) { winner[0] = tx0; winner[1] = tx0; winner[2] = tx1; }
        else if (K == 1) { winner[0] = tx0; winner[1] = tx0; winner[2] = tx0; }
        else             { winner[0] = -1;  winner[1] = -1;  winner[2] = -1;  }
    }
    __syncthreads();

    // P6: recompute bboxes for just the 3 winning components
    {
        int row = tid >> 3;
        int w0 = (tid & 7) * 16;
        ull lo = rowmask[row][0], hi = rowmask[row][1];
        ull rs_lo = rsmask[row][0], rs_hi = rsmask[row][1];
        ull seg = ((w0 < 64) ? (rs_lo >> w0) : (rs_hi >> (w0 - 64))) & 0xFFFFULL;
        int wn0 = winner[0], wn1 = winner[1], wn2 = winner[2];
        while (seg) {
            int c = w0 + (__ffsll(seg) - 1);
            seg &= seg - 1;
            int rid = (row << 6) + run_index(rs_lo, rs_hi, c);
            int v = parent[rid];
            int idx = (v >= NRUN) ? (v - NRUN) : (parent[v] - NRUN);
            if (idx != wn0 && idx != wn1 && idx != wn2) continue;
            int e = run_end_col(lo, hi, c);
            #pragma unroll
            for (int s = 0; s < 3; ++s) {
                int wn = (s == 0) ? wn0 : (s == 1) ? wn1 : wn2;
                if (idx == wn) {
                    atomicMin(&w_minr[s], row);
                    atomicMax(&w_maxr[s], row);
                    atomicMin(&w_minc[s], c);
                    atomicMax(&w_maxc[s], e);
                }
            }
        }
    }
    __syncthreads();

    if (tid < 3) {
        int s = tid;
        int mr, h, mc, w;
        if (winner[s] < 0) { mr = 0; h = HH; mc = 0; w = WW_; }
        else {
            mr = w_minr[s]; h = w_maxr[s] + 1 - mr;
            mc = w_minc[s]; w = w_maxc[s] + 1 - mc;
        }
        int* o = bbox + (b * 3 + s) * 4;
        o[0] = mr; o[1] = h; o[2] = mc; o[3] = w;
    }
}

// ---------------------------------------------------------------------------
// Kernel 2: nearest-neighbor crop-resize gather. One float4 store per thread.
// out[b, slot*192+c, y, x] = feat[b, c, mr + (y*h)>>6, mc + (x*w)>>6]
// ---------------------------------------------------------------------------

__global__ __launch_bounds__(256) void crop_kernel(
    const float* __restrict__ feat, const int* __restrict__ bbox,
    float* __restrict__ out)
{
    const int gid = blockIdx.x * 256 + threadIdx.x;   // 9,437,184 total
    const int x4 = gid & 15;
    const int y  = (gid >> 4) & 63;
    const int t  = gid >> 10;        // (b*3+slot)*192 + c, 0..9215
    const int c  = t % CF;
    const int bs = t / CF;           // b*3+slot, 0..47
    const int* bb = bbox + bs * 4;
    const int mr = bb[0], h = bb[1], mc = bb[2], w = bb[3];
    const int r = mr + ((y * h) >> 6);
    const int bimg = bs / 3;
    const float* row = feat + (((size_t)bimg * CF + c) * HH + r) * WW_;
    const int x = x4 * 4;
    vf4 v;
    v.x = row[mc + (((x + 0) * w) >> 6)];
    v.y = row[mc + (((x + 1) * w) >> 6)];
    v.z = row[mc + (((x + 2) * w) >> 6)];
    v.w = row[mc + (((x + 3) * w) >> 6)];
    __builtin_nontemporal_store(v, (vf4*)out + gid);  // streaming store
}

// ---------------------------------------------------------------------------

extern "C" void kernel_launch(void* const* d_in, const int* in_sizes, int n_in,
                              void* d_out, int out_size, void* d_ws, size_t ws_size,
                              hipStream_t stream) {
    const float* prob = (const float*)d_in[0];   // [16,1,128,128]
    const float* feat = (const float*)d_in[1];   // [16,192,128,128]
    float* out = (float*)d_out;                  // [16,576,64,64]

    int* bbox = (int*)d_ws;                      // [16][3][4] ints, fully written

    hipLaunchKernelGGL(ccl_kernel, dim3(NB), dim3(1024), 0, stream,
                       prob, bbox);
    const int total4 = NB * 3 * CF * H2 * (W2 / 4);   // 9,437,184 float4s
    hipLaunchKernelGGL(crop_kernel, dim3(total4 / 256), dim3(256), 0, stream,
                       feat, bbox, out);
}